// Round 8
// baseline (220.695 us; speedup 1.0000x reference)
//
#include <hip/hip_runtime.h>

// Problem constants (fixed by the reference).
constexpr int S1 = 8, S2 = 8, F = 128;
constexpr int ROWS_PER_BRANCH = S1 * (2 + 2 * S2);   // 144
constexpr int ROWS_PER_B = 2 * ROWS_PER_BRANCH;      // 288
constexpr int TOTAL_ROWS = 2048 * ROWS_PER_B;        // 589824
constexpr int NNODES = 100000;
constexpr int SCAN_BLK = 1024;
constexpr int NBLK = (NNODES + SCAN_BLK - 1) / SCAN_BLK;  // 98
// flat f32x2 slot domain: 589824*65 = 38,338,560 = 9360*256*16
constexpr unsigned TOTAL_THREADS = 9360u * 256u;     // 2,396,160
constexpr int SLOTS_PER_THREAD = 16;

typedef float f32x2 __attribute__((ext_vector_type(2)));
typedef unsigned int u32;

// d_ws layout (bytes, all 16-aligned):
//   meta  int4[TOTAL_ROWS] @ 0            9,437,184
//   nodeA u32 [TOTAL_ROWS] @  9,437,184   2,359,296
//   order u32 [TOTAL_ROWS] @ 11,796,480   2,359,296
//   bins  u32 [NNODES]     @ 14,155,776     400,000
//   bsum  u32 [128]        @ 14,555,776
constexpr size_t OFF_NODEA = 9437184;
constexpr size_t OFF_ORDER = 11796480;
constexpr size_t OFF_BINS  = 14155776;
constexpr size_t OFF_BSUM  = 14555776;

// A: resolve {node, wf, wt} per row; histogram nodes.
__global__ __launch_bounds__(256) void gae_meta(
    const float* __restrict__ in_amnt,
    const float* __restrict__ out_amnt,
    const int*   __restrict__ in_sample,
    const int*   __restrict__ out_sample,
    const int*   __restrict__ node_ids,
    int4* __restrict__ meta, u32* __restrict__ nodeA, u32* __restrict__ bins)
{
    const int row = blockIdx.x * blockDim.x + threadIdx.x;  // exact grid
    const int b  = row / ROWS_PER_B;
    const int r  = row - b * ROWS_PER_B;
    const int d1 = r / ROWS_PER_BRANCH;
    const int rr = r - d1 * ROWS_PER_BRANCH;
    const int s1 = rr / 18;
    const int lr = rr - s1 * 18;

    const int   nid = node_ids[b];
    const int   e1  = nid * S1 + s1;
    const int   n1  = d1 ? out_sample[e1] : in_sample[e1];
    const float w1  = d1 ? out_amnt[e1]   : in_amnt[e1];

    int node; float wf, wt;
    if (lr == 0 || lr == 9) {
        node = n1; wf = w1; wt = w1 * w1;
    } else if (lr <= 8) {
        const int e2 = n1 * S2 + (lr - 1);
        const float w2 = in_amnt[e2];
        node = in_sample[e2]; wf = w2; wt = w2 * w1;
    } else {
        const int e2 = n1 * S2 + (lr - 10);
        const float w2 = out_amnt[e2];
        node = out_sample[e2]; wf = w2; wt = w2 * w1;
    }

    int4 m; m.x = node; m.y = __float_as_int(wf); m.z = __float_as_int(wt); m.w = 0;
    meta[row]  = m;
    nodeA[row] = (u32)node;
    atomicAdd(&bins[node], 1u);
}

// B1: per-1024-block exclusive scan of bins (in place) + block totals.
__global__ __launch_bounds__(SCAN_BLK) void scan1(u32* __restrict__ bins,
                                                  u32* __restrict__ bsum)
{
    __shared__ u32 tmp[SCAN_BLK];
    const int t = threadIdx.x;
    const int i = blockIdx.x * SCAN_BLK + t;
    const u32 c = (i < NNODES) ? bins[i] : 0u;
    tmp[t] = c;
    __syncthreads();
    for (int off = 1; off < SCAN_BLK; off <<= 1) {
        const u32 v = tmp[t];
        const u32 a = (t >= off) ? tmp[t - off] : 0u;
        __syncthreads();
        tmp[t] = v + a;
        __syncthreads();
    }
    if (i < NNODES) bins[i] = tmp[t] - c;            // exclusive within block
    if (t == SCAN_BLK - 1) bsum[blockIdx.x] = tmp[t];
}

// B2: exclusive scan of the 98 block totals (serial, trivial size).
__global__ void scan2(u32* __restrict__ bsum)
{
    if (threadIdx.x == 0 && blockIdx.x == 0) {
        u32 run = 0;
        for (int b = 0; b < NBLK; ++b) { const u32 v = bsum[b]; bsum[b] = run; run += v; }
    }
}

// B3: add block bases -> bins[] = global exclusive offsets.
__global__ __launch_bounds__(SCAN_BLK) void scan3(u32* __restrict__ bins,
                                                  const u32* __restrict__ bsum)
{
    const int i = blockIdx.x * SCAN_BLK + threadIdx.x;
    if (i < NNODES) bins[i] += bsum[blockIdx.x];
}

// C: place rows into node-sorted order.
__global__ __launch_bounds__(256) void gae_place(
    const u32* __restrict__ nodeA, u32* __restrict__ bins, u32* __restrict__ order)
{
    const int row = blockIdx.x * blockDim.x + threadIdx.x;  // exact grid
    const u32 node = nodeA[row];
    const u32 pos  = atomicAdd(&bins[node], 1u);
    order[pos] = (u32)row;
}

// D: flat-slot scatter through the sorted permutation. Feature table is
// swept in ascending node order (stream-like reads); output rows written
// where they belong (row-contiguous 520B runs, random order).
// Row slots: [wf f0][f1 f2]...[f125 f126][f127 wt].
__global__ __launch_bounds__(256) void gae_scatter(
    const float* __restrict__ features,
    const int4*  __restrict__ meta,
    const u32*   __restrict__ order,
    float*       __restrict__ out)
{
    const u32 tid = blockIdx.x * blockDim.x + threadIdx.x;
    f32x2* __restrict__ out2 = (f32x2*)out;

    #pragma unroll 4
    for (int k = 0; k < SLOTS_PER_THREAD; ++k) {
        const u32 s   = tid + (u32)k * TOTAL_THREADS;
        const u32 kk  = s / 65u;                     // sorted row index
        const u32 j   = s - kk * 65u;
        const u32 row = order[kk];

        const int4  m  = meta[row];
        const float wf = __int_as_float(m.y);
        const float wt = __int_as_float(m.z);
        const float* __restrict__ frow = features + (size_t)m.x * F;

        const u32 iA = (j == 0u)  ? 0u   : (2u * j - 1u);
        const u32 iB = (j >= 64u) ? 127u : (2u * j);
        const float a  = frow[iA];
        const float bv = frow[iB];

        f32x2 v;
        v.x = (j == 0u)  ? wf : a;
        v.y = (j == 64u) ? wt : bv;
        __builtin_nontemporal_store(v, &out2[(size_t)row * 65u + j]);
    }
}

extern "C" void kernel_launch(void* const* d_in, const int* in_sizes, int n_in,
                              void* d_out, int out_size, void* d_ws, size_t ws_size,
                              hipStream_t stream) {
    const float* features   = (const float*)d_in[0];
    const float* in_amnt    = (const float*)d_in[1];
    const float* out_amnt   = (const float*)d_in[2];
    const int*   in_sample  = (const int*)d_in[3];
    const int*   out_sample = (const int*)d_in[4];
    const int*   node_ids   = (const int*)d_in[5];
    float*       out        = (float*)d_out;

    char* ws    = (char*)d_ws;
    int4* meta  = (int4*)ws;
    u32*  nodeA = (u32*)(ws + OFF_NODEA);
    u32*  order = (u32*)(ws + OFF_ORDER);
    u32*  bins  = (u32*)(ws + OFF_BINS);
    u32*  bsum  = (u32*)(ws + OFF_BSUM);

    hipMemsetAsync(bins, 0, NNODES * sizeof(u32), stream);
    gae_meta<<<TOTAL_ROWS / 256, 256, 0, stream>>>(in_amnt, out_amnt, in_sample,
                                                   out_sample, node_ids,
                                                   meta, nodeA, bins);
    scan1<<<NBLK, SCAN_BLK, 0, stream>>>(bins, bsum);
    scan2<<<1, 64, 0, stream>>>(bsum);
    scan3<<<NBLK, SCAN_BLK, 0, stream>>>(bins, bsum);
    gae_place<<<TOTAL_ROWS / 256, 256, 0, stream>>>(nodeA, bins, order);
    gae_scatter<<<9360, 256, 0, stream>>>(features, meta, order, out);
}

// Round 9
// 102.880 us; speedup vs baseline: 2.1452x; 2.1452x over previous
//
#include <hip/hip_runtime.h>

// Problem constants (fixed by the reference).
constexpr int S1 = 8, S2 = 8, F = 128;
constexpr int ROWS_PER_BRANCH = S1 * (2 + 2 * S2);   // 144
constexpr int ROWS_PER_B = 2 * ROWS_PER_BRANCH;      // 288
constexpr int ROW_LEN = F + 2;                       // 130
constexpr int TOTAL_ROWS = 2048 * ROWS_PER_B;        // 589824
// TOTAL f32x2 slots = 589824*65 = 38,338,560 = 9360*256 threads * 16
constexpr unsigned TOTAL_THREADS = 9360u * 256u;     // 2,396,160
constexpr int BATCH_SLOTS = 8;                       // slots per phase-group
constexpr int NGROUPS = 2;                           // 2 x 8 = 16 slots/thread

typedef float f32x2 __attribute__((ext_vector_type(2)));
typedef unsigned int u32;

// Kernel 1: resolve every output row's {node, wf, wt} -> meta[] in d_ws.
// One thread per row; the 3-deep index chase runs 590K-wide in parallel.
__global__ __launch_bounds__(256) void gae_meta(
    const float* __restrict__ in_amnt,
    const float* __restrict__ out_amnt,
    const int*   __restrict__ in_sample,
    const int*   __restrict__ out_sample,
    const int*   __restrict__ node_ids,
    int4*        __restrict__ meta)
{
    const int row = blockIdx.x * blockDim.x + threadIdx.x;  // exact grid
    const int b  = row / ROWS_PER_B;
    const int r  = row - b * ROWS_PER_B;
    const int d1 = r / ROWS_PER_BRANCH;              // 0='in' branch, 1='out'
    const int rr = r - d1 * ROWS_PER_BRANCH;
    const int s1 = rr / 18;
    const int lr = rr - s1 * 18;

    const int   nid = node_ids[b];
    const int   e1  = nid * S1 + s1;
    const int   n1  = d1 ? out_sample[e1] : in_sample[e1];
    const float w1  = d1 ? out_amnt[e1]   : in_amnt[e1];

    int node; float wf, wt;
    if (lr == 0 || lr == 9) {                        // hub-1 row (twice)
        node = n1; wf = w1; wt = w1 * w1;
    } else if (lr <= 8) {                            // hub-2, in-direction
        const int e2 = n1 * S2 + (lr - 1);
        const float w2 = in_amnt[e2];
        node = in_sample[e2]; wf = w2; wt = w2 * w1;
    } else {                                         // hub-2, out-direction
        const int e2 = n1 * S2 + (lr - 10);
        const float w2 = out_amnt[e2];
        node = out_sample[e2]; wf = w2; wt = w2 * w1;
    }

    int4 m;
    m.x = node;
    m.y = __float_as_int(wf);
    m.z = __float_as_int(wt);
    m.w = 0;
    meta[row] = m;
}

// Kernel 2: one thread per f32x2 output slot, flat slot space (every wave's
// stores 512B contiguous+aligned). Row slots: [wf f0][f1 f2]...[f127 wt].
__global__ __launch_bounds__(256) void gae_scatter(
    const float* __restrict__ features,
    const int4*  __restrict__ meta,
    float*       __restrict__ out)
{
    const u32 tid = blockIdx.x * blockDim.x + threadIdx.x;
    f32x2* __restrict__ out2 = (f32x2*)out;

    #pragma unroll
    for (int g = 0; g < NGROUPS; ++g) {
        u32   sv[BATCH_SLOTS];
        float wfv[BATCH_SLOTS], wtv[BATCH_SLOTS];
        float av[BATCH_SLOTS], bv[BATCH_SLOTS];
        u32   jv[BATCH_SLOTS];

        // ---- load phase: all requests independent ----
        #pragma unroll
        for (int k = 0; k < BATCH_SLOTS; ++k) {
            const u32 s   = tid + (u32)(g * BATCH_SLOTS + k) * TOTAL_THREADS;
            const u32 row = s / 65u;                 // magic-mul div
            const u32 j   = s - row * 65u;
            sv[k] = s; jv[k] = j;

            const int4 m = meta[row];                // L1-shared across row
            wfv[k] = __int_as_float(m.y);
            wtv[k] = __int_as_float(m.z);
            const float* __restrict__ frow = features + (size_t)m.x * F;

            const u32 iA = (j == 0u)  ? 0u   : (2u * j - 1u);
            const u32 iB = (j >= 64u) ? 127u : (2u * j);
            av[k] = frow[iA];
            bv[k] = frow[iB];
        }

        // ---- store phase: 8 nt stores burst back-to-back ----
        #pragma unroll
        for (int k = 0; k < BATCH_SLOTS; ++k) {
            f32x2 v;
            v.x = (jv[k] == 0u)  ? wfv[k] : av[k];
            v.y = (jv[k] == 64u) ? wtv[k] : bv[k];
            __builtin_nontemporal_store(v, &out2[sv[k]]);
        }
    }
}

extern "C" void kernel_launch(void* const* d_in, const int* in_sizes, int n_in,
                              void* d_out, int out_size, void* d_ws, size_t ws_size,
                              hipStream_t stream) {
    const float* features   = (const float*)d_in[0];
    const float* in_amnt    = (const float*)d_in[1];
    const float* out_amnt   = (const float*)d_in[2];
    const int*   in_sample  = (const int*)d_in[3];
    const int*   out_sample = (const int*)d_in[4];
    const int*   node_ids   = (const int*)d_in[5];
    float*       out        = (float*)d_out;
    int4*        meta       = (int4*)d_ws;           // 9.4 MB of d_ws

    gae_meta<<<TOTAL_ROWS / 256, 256, 0, stream>>>(in_amnt, out_amnt,
                                                   in_sample, out_sample,
                                                   node_ids, meta);
    gae_scatter<<<9360, 256, 0, stream>>>(features, meta, out);
}